// Round 11
// baseline (316.249 us; speedup 1.0000x reference)
//
#include <hip/hip_runtime.h>

#define T_N   1024
#define B_N   64
#define CIN   32
#define COUT  32
#define MODES 16
#define DT    0.01f
#define PI_F  3.14159265358979323846f
#define W_SCALE 0.613592315154256f   /* 2*pi/(T_N*DT) */
#define W_NYQ  (-314.1592653589793f) /* -pi/DT */

// ---------------------------------------------------------------------------
// Radix-2 Stockham FFT, length 1024, LDS twiddle table.
// ---------------------------------------------------------------------------
template <int SIGN>
__device__ __forceinline__ void fft1024(float2* A, float2* B, const float2* TW, int tid) {
    float2* src = A;
    float2* dst = B;
    int m = 1;
#pragma unroll
    for (int s = 0; s < 10; ++s) {
        __syncthreads();
#pragma unroll
        for (int r = 0; r < 2; ++r) {
            int idx = tid + (r << 8);
            int k = idx & (m - 1);
            int j = idx >> s;
            float2 c0 = src[k + j * m];
            float2 c1 = src[k + j * m + 512];
            float2 w = TW[(j << s)];
            float ex = c0.x - c1.x, ey = c0.y - c1.y;
            dst[k + 2 * j * m]     = make_float2(c0.x + c1.x, c0.y + c1.y);
            dst[k + 2 * j * m + m] = make_float2(w.x * ex - w.y * ey, w.x * ey + w.y * ex);
        }
        float2* t = src; src = dst; dst = t;
        m <<= 1;
    }
    __syncthreads();
}

template <int SIGN>
__device__ __forceinline__ void build_tw(float2* TW, int tid) {
#pragma unroll
    for (int r = 0; r < 2; ++r) {
        int a = tid + (r << 8);
        float sn, cs;
        __sincosf((float)SIGN * PI_F * (float)a * (1.0f / 512.0f), &sn, &cs);
        TW[a] = make_float2(cs, sn);
    }
}

__global__ __launch_bounds__(256) void k_fft_fwd(const float* __restrict__ x,
                                                 float2* __restrict__ alpha) {
    __shared__ float2 A[1024];
    __shared__ float2 Bb[1024];
    __shared__ float2 TW[512];
    int row = blockIdx.x;
    int tid = threadIdx.x;
    build_tw<-1>(TW, tid);
    const float* xr = x + (size_t)row * T_N;
#pragma unroll
    for (int r = 0; r < 4; ++r) {
        int j = tid + (r << 8);
        A[j] = make_float2(xr[j], 0.0f);
    }
    fft1024<-1>(A, Bb, TW, tid);
    float2* outp = alpha + (size_t)row * T_N;
#pragma unroll
    for (int r = 0; r < 4; ++r) {
        int j = tid + (r << 8);
        outp[j] = A[j];
    }
}

// ---------------------------------------------------------------------------
// transpose alpha[(b*CIN+i)][x] -> alphaT[i][x][b]
// ---------------------------------------------------------------------------
__global__ __launch_bounds__(256) void k_transpose_a(const float2* __restrict__ alpha,
                                                     float2* __restrict__ alphaT) {
    __shared__ float2 T[32 * 66];
    int blk = blockIdx.x;
    int i = blk >> 5, xt = blk & 31;
    int tid = threadIdx.x;
#pragma unroll
    for (int r = 0; r < 8; ++r) {
        int e = tid + (r << 8);
        int xx = e & 31, b = e >> 5;
        T[xx * 66 + b] = alpha[((size_t)(b * CIN + i)) * T_N + xt * 32 + xx];
    }
    __syncthreads();
#pragma unroll
    for (int r = 0; r < 8; ++r) {
        int e = tid + (r << 8);
        int b = e & 63, xx = e >> 6;
        alphaT[((size_t)i * T_N + xt * 32 + xx) * B_N + b] = T[xx * 66 + b];
    }
}

// ---------------------------------------------------------------------------
// out1: per-frequency mixing (unchanged — works).
// ---------------------------------------------------------------------------
__global__ __launch_bounds__(256) void k_out1(const float4* __restrict__ alphaT4,
                                              const float* __restrict__ pr,
                                              const float* __restrict__ pim,
                                              const float* __restrict__ rr,
                                              const float* __restrict__ ri,
                                              float2* __restrict__ out1tmp) {
    __shared__ float sARe[32 * 64];
    __shared__ float sAIm[32 * 64];
    __shared__ float2 Hs[32 * 32];
    int x = blockIdx.x;
    int tid = threadIdx.x;

#pragma unroll
    for (int r = 0; r < 4; ++r) {
        int e = tid + (r << 8);
        int i = e >> 5, bp = e & 31;
        float4 v = alphaT4[((size_t)i * T_N + x) * (B_N / 2) + bp];
        *(float2*)&sARe[i * 64 + bp * 2] = make_float2(v.x, v.z);
        *(float2*)&sAIm[i * 64 + bp * 2] = make_float2(v.y, v.w);
    }

    int fx = x - ((x >= 512) ? 1024 : 0);
    float w = (float)fx * W_SCALE;
#pragma unroll
    for (int r = 0; r < 4; ++r) {
        int e = tid + (r << 8);
        int i = e >> 5, o = e & 31;
        int base = (i * COUT + o) * MODES;
        float hr = 0.f, hi = 0.f;
#pragma unroll
        for (int k = 0; k < MODES; ++k) {
            float a = pr[base + k], bI = pim[base + k];
            float d = w - bI;
            float inv = 1.0f / (a * a + d * d);
            float vR = -a * inv, vI = -d * inv;
            float sR = rr[base + k], sI = ri[base + k];
            hr += sR * vR - sI * vI;
            hi += sR * vI + sI * vR;
        }
        Hs[i * 32 + o] = make_float2(hr, hi);
    }
    __syncthreads();

    int o = tid & 31, bg = tid >> 5;
    float accR[8] = {}, accI[8] = {};
#pragma unroll 2
    for (int i = 0; i < CIN; ++i) {
        float2 h = Hs[i * 32 + o];
        float4 ar0 = *(const float4*)&sARe[i * 64 + bg * 8];
        float4 ar1 = *(const float4*)&sARe[i * 64 + bg * 8 + 4];
        float4 ai0 = *(const float4*)&sAIm[i * 64 + bg * 8];
        float4 ai1 = *(const float4*)&sAIm[i * 64 + bg * 8 + 4];
        float aR[8] = {ar0.x, ar0.y, ar0.z, ar0.w, ar1.x, ar1.y, ar1.z, ar1.w};
        float aI[8] = {ai0.x, ai0.y, ai0.z, ai0.w, ai1.x, ai1.y, ai1.z, ai1.w};
#pragma unroll
        for (int bb = 0; bb < 8; ++bb) {
            accR[bb] += aR[bb] * h.x - aI[bb] * h.y;
            accI[bb] += aR[bb] * h.y + aI[bb] * h.x;
        }
    }
#pragma unroll
    for (int bb = 0; bb < 8; ++bb) {
        out1tmp[(size_t)x * 2048 + (bg * 8 + bb) * 32 + o] =
            make_float2(accR[bb], accI[bb]);
    }
}

// ---------------------------------------------------------------------------
// out2 v11: 8b x 4k x 1o thread tile (reads/FMA halved vs v10).
// out2[b,o,k] = sum_i sum_{x=0..511} aR*C1 + aI*C2 (conjugate-folded).
// Grid dim3(og:4, xq:xq_n, i:32), 256 thr = bg(8) x kg(4) x oq(8).
// chunk=(i,xq): 32*xq_n chunks of 256KB. Same-slice blocks id-consecutive.
// NO min-waves clamp (spill tripwire: WRITE_SIZE must stay 32MB).
// ---------------------------------------------------------------------------
#define AROW4 36    /* f4 per alpha row: slot(bp)=bp+(bp>>3), max 34 */
#define VROW4 136   /* f4 per V row: slot(op,k)=op*17+k, op<8 -> max 134 */
__global__ __launch_bounds__(256) void k_out2(const float4* __restrict__ alphaT4,
                                              const float* __restrict__ pr,
                                              const float* __restrict__ pim,
                                              const float* __restrict__ rr,
                                              const float* __restrict__ ri,
                                              float2* __restrict__ partial) {
    __shared__ __align__(16) float4 sA[8 * AROW4];   // 4.6 KB
    __shared__ __align__(16) float4 sV[8 * VROW4];   // 17.4 KB
    __shared__ float sPol[4][128];

    const int og = blockIdx.x, xq = blockIdx.y, i = blockIdx.z;
    const int xq_n = gridDim.y;
    const int K_xx = 512 / xq_n;
    const int nt = K_xx >> 3;
    const int xbase = xq * K_xx;
    const int tid = threadIdx.x;
    const int bg = tid & 7;             // 8 b's: b = bg*8+bi
    const int kg = (tid >> 3) & 3;      // 4 k's: k = kg*4+kk
    const int oq = tid >> 5;            // o' within block (0..7)
    const int sbase = bg * 4 + (bg >> 1);   // A f4 slot base for this thread

    if (tid < 128) {
        int oo = tid >> 4, k = tid & 15;
        int pidx = (i * COUT + og * 8 + oo) * MODES + k;
        sPol[0][tid] = pr[pidx]; sPol[1][tid] = pim[pidx];
        sPol[2][tid] = rr[pidx]; sPol[3][tid] = ri[pidx];
    }
    __syncthreads();

    float accR[8][4] = {}, accI[8][4] = {};

    for (int t = 0; t < nt; ++t) {
        int x0 = xbase + t * 8;
        __syncthreads();
        // stage alpha tile [8 xx][64 b] (256 f4, coalesced read, padded write)
        {
            int xx = tid >> 5, bp = tid & 31;
            float4 v = alphaT4[((size_t)i * T_N + x0 + xx) * 32 + bp];
            sA[xx * AROW4 + bp + (bp >> 3)] = v;
        }
        // V table: [8 xx][8 o'][16 k] f4 = (C1r,C1i,C2r,C2i)
#pragma unroll
        for (int r = 0; r < 4; ++r) {
            int e = tid + (r << 8);          // 0..1023: xx=e>>7, rem=e&127
            int xx = e >> 7, rem = e & 127;
            int op = rem >> 4, k = rem & 15;
            int xg = x0 + xx;
            float a = sPol[0][rem], bI = sPol[1][rem];
            float sR = sPol[2][rem], sI = sPol[3][rem];
            float c1r, c1i, c2r, c2i;
            if (xg == 0) {
                float s1 = a * a + bI * bI;
                float q1r = a / s1, q1i = -bI / s1;
                c1r = sR * q1r - sI * q1i;
                c1i = sR * q1i + sI * q1r;
                float dr = -a, di = W_NYQ - bI;
                float s2 = dr * dr + di * di;
                float q2r = dr / s2, q2i = -di / s2;
                c2r = -(sR * q2r - sI * q2i);
                c2i = -(sR * q2i + sI * q2r);
            } else {
                float w = (float)xg * W_SCALE;
                float denr = a * a - bI * bI + w * w;
                float deni = 2.0f * a * bI;
                float s = denr * denr + deni * deni;
                float qr = denr / s, qi = -deni / s;
                float prr = a * sR - bI * sI;
                float pri = a * sI + bI * sR;
                c1r = 2.0f * (prr * qr - pri * qi);
                c1i = 2.0f * (prr * qi + pri * qr);
                float rqr = sR * qr - sI * qi;
                float rqi = sR * qi + sI * qr;
                c2r = -2.0f * w * rqr;
                c2i = -2.0f * w * rqi;
            }
            sV[xx * VROW4 + op * 17 + k] = make_float4(c1r, c1i, c2r, c2i);
        }
        __syncthreads();
        if (xq == 0 && t == 0) {
            // patch x=0 row: imag slots <- Re(alpha[b,i,512]) for all 64 b
            if (tid < 32) {
                float4 v = alphaT4[((size_t)i * T_N + 512) * 32 + tid];
                float* sAf = (float*)sA;
                int slot = tid + (tid >> 3);   // slot(bp=tid)
                sAf[slot * 4 + 1] = v.x;       // b = 2*tid
                sAf[slot * 4 + 3] = v.z;       // b = 2*tid+1
            }
            __syncthreads();
        }

        // MAC: 8b x 4k per thread per xx (8 b128 reads : 128 FMA)
#pragma unroll
        for (int xx = 0; xx < 8; ++xx) {
            const float4* ap = &sA[xx * AROW4 + sbase];
            float4 a0 = ap[0], a1 = ap[1], a2 = ap[2], a3 = ap[3];
            const float4* vp = &sV[xx * VROW4 + oq * 17 + kg * 4];
            float4 v0 = vp[0], v1 = vp[1], v2 = vp[2], v3 = vp[3];
            float aR[8] = {a0.x, a0.z, a1.x, a1.z, a2.x, a2.z, a3.x, a3.z};
            float aI[8] = {a0.y, a0.w, a1.y, a1.w, a2.y, a2.w, a3.y, a3.w};
            float C1r[4] = {v0.x, v1.x, v2.x, v3.x};
            float C1i[4] = {v0.y, v1.y, v2.y, v3.y};
            float C2r[4] = {v0.z, v1.z, v2.z, v3.z};
            float C2i[4] = {v0.w, v1.w, v2.w, v3.w};
#pragma unroll
            for (int bi = 0; bi < 8; ++bi)
#pragma unroll
                for (int kk = 0; kk < 4; ++kk) {
                    accR[bi][kk] += aR[bi] * C1r[kk] + aI[bi] * C2r[kk];
                    accI[bi][kk] += aR[bi] * C1i[kk] + aI[bi] * C2i[kk];
                }
        }
    }

    // write partial chunk (i,xq): [b][o][k] float2, 32B contiguous per lane
    int chunk = i * xq_n + xq;
    int o = og * 8 + oq;
    float2* dst = partial + (size_t)chunk * (B_N * COUT * MODES);
#pragma unroll
    for (int bi = 0; bi < 8; ++bi) {
        int b = bg * 8 + bi;
        int base = (b * COUT + o) * MODES + kg * 4;   // float2 index, even
        float4* p = (float4*)(dst + base);
        p[0] = make_float4(accR[bi][0], accI[bi][0], accR[bi][1], accI[bi][1]);
        p[1] = make_float4(accR[bi][2], accI[bi][2], accR[bi][3], accI[bi][3]);
    }
}

// ---------------------------------------------------------------------------
// reduce nchunk partials into o2[b][o][k]
// ---------------------------------------------------------------------------
__global__ __launch_bounds__(256) void k_reduce(const float4* __restrict__ p,
                                                float4* __restrict__ o2, int nchunk) {
    int f = blockIdx.x * 256 + threadIdx.x;   // 16384 float4s
    float4 s = make_float4(0.f, 0.f, 0.f, 0.f);
    for (int c = 0; c < nchunk; ++c) {
        float4 v = p[(size_t)c * 16384 + f];
        s.x += v.x; s.y += v.y; s.z += v.z; s.w += v.w;
    }
    o2[f] = s;
}

// ---------------------------------------------------------------------------
// transpose out1tmp[x][bo] -> out1T[bo][x]
// ---------------------------------------------------------------------------
__global__ __launch_bounds__(256) void k_transpose_o1(const float2* __restrict__ out1tmp,
                                                      float2* __restrict__ out1T) {
    __shared__ float2 T[64 * 33];
    int blk = blockIdx.x;
    int bot = blk >> 5, xt = blk & 31;
    int tid = threadIdx.x;
#pragma unroll
    for (int r = 0; r < 8; ++r) {
        int e = tid + (r << 8);
        int j = e & 63, xr = e >> 6;
        T[j * 33 + xr] = out1tmp[((size_t)(xt * 32 + xr)) * 2048 + bot * 64 + j];
    }
    __syncthreads();
#pragma unroll
    for (int r = 0; r < 8; ++r) {
        int e = tid + (r << 8);
        int xx = e & 31, j = e >> 5;
        out1T[((size_t)(bot * 64 + j)) * T_N + xt * 32 + xx] = T[j * 33 + xx];
    }
}

__global__ __launch_bounds__(256) void k_ifft(const float2* __restrict__ out1T,
                                              float* __restrict__ outp) {
    __shared__ float2 A[1024];
    __shared__ float2 Bb[1024];
    __shared__ float2 TW[512];
    int row = blockIdx.x;
    int tid = threadIdx.x;
    build_tw<1>(TW, tid);
    const float2* src = out1T + (size_t)row * T_N;
#pragma unroll
    for (int r = 0; r < 4; ++r) {
        int j = tid + (r << 8);
        A[j] = src[j];
    }
    fft1024<1>(A, Bb, TW, tid);
    float* dst = outp + (size_t)row * T_N;
    const float inv_n = 1.0f / (float)T_N;
#pragma unroll
    for (int r = 0; r < 4; ++r) {
        int j = tid + (r << 8);
        dst[j] = A[j].x * inv_n;
    }
}

// ---------------------------------------------------------------------------
// x2 v11: 8b x 8z thread tile, 128 thr. grid dim3(cmh:4, zt:8, o:32).
// Reads per j: 4 P-f4 + 4 E-f4 : 128 FMA.
// ---------------------------------------------------------------------------
#define PROW 100    /* floats per P row: 8 groups of (8 data + 4 pad) */
#define EROWF 140   /* floats per E row: z + ((z>>5)<<2), max 139 */
__global__ __launch_bounds__(128) void k_x2(const float4* __restrict__ o2f4,
                                            const float* __restrict__ pr,
                                            const float* __restrict__ pim,
                                            float* __restrict__ partial) {
    __shared__ __align__(16) float sPre[16 * PROW], sPim_[16 * PROW];
    __shared__ __align__(16) float sEre[16 * EROWF], sEim[16 * EROWF];
    __shared__ float s_pr[128], s_pim[128];

    const int cmh = blockIdx.x, zt = blockIdx.y, o = blockIdx.z;
    const int tid = threadIdx.x;
    const int zq = tid & 15, bq = tid >> 4;      // 8 z's, 8 b's per thread
    const int cmBase = cmh * 128;
    const int ebase = zq * 8 + (zq >> 2) * 4;    // padded float offset for 8 z

    {
        int cm = cmBase + tid;
        int c = cm >> 4, m = cm & 15;
        int pidx = (c * COUT + o) * MODES + m;
        s_pr[tid] = pr[pidx];
        s_pim[tid] = pim[pidx];
    }

    float acc[8][8] = {};

    for (int t = 0; t < 8; ++t) {
        int cm0l = t * 16;
        __syncthreads();
        // stage P tile [16 j][64 b]
#pragma unroll
        for (int r = 0; r < 4; ++r) {
            int e = tid + (r << 7);              // 0..511: b=e>>3, jp=e&7
            int b = e >> 3, jp = e & 7;
            float4 v = o2f4[b * 256 + ((cmBase + cm0l) >> 1) + jp];
            int j0 = jp * 2;
            int pa = (b >> 3) * 12 + (b & 7);
            sPre[j0 * PROW + pa] = v.x;
            sPim_[j0 * PROW + pa] = v.y;
            sPre[(j0 + 1) * PROW + pa] = v.z;
            sPim_[(j0 + 1) * PROW + pa] = v.w;
        }
        // E tile [16 j][128 z] (padded rows)
#pragma unroll
        for (int r = 0; r < 16; ++r) {
            int e = tid + (r << 7);              // 0..2047: z=e&127, j=e>>7
            int z = e & 127, j = e >> 7;
            float gr = s_pr[cm0l + j], gi = s_pim[cm0l + j];
            float tz = (float)(zt * 128 + z) * DT;
            float er = __expf(gr * tz);
            float sn, cn;
            __sincosf(gi * tz, &sn, &cn);
            int zo = z + ((z >> 5) << 2);
            sEre[j * EROWF + zo] = er * cn;
            sEim[j * EROWF + zo] = er * sn;
        }
        __syncthreads();

#pragma unroll 2
        for (int j = 0; j < 16; ++j) {
            const float* pp = &sPre[j * PROW + bq * 12];
            const float* qq = &sPim_[j * PROW + bq * 12];
            float4 p0 = *(const float4*)&pp[0];
            float4 p1 = *(const float4*)&pp[4];
            float4 q0 = *(const float4*)&qq[0];
            float4 q1 = *(const float4*)&qq[4];
            const float* ep = &sEre[j * EROWF + ebase];
            const float* fp = &sEim[j * EROWF + ebase];
            float4 e0 = *(const float4*)&ep[0];
            float4 e1 = *(const float4*)&ep[4];
            float4 f0 = *(const float4*)&fp[0];
            float4 f1 = *(const float4*)&fp[4];
            float PRe[8] = {p0.x, p0.y, p0.z, p0.w, p1.x, p1.y, p1.z, p1.w};
            float PIm[8] = {q0.x, q0.y, q0.z, q0.w, q1.x, q1.y, q1.z, q1.w};
            float ERe[8] = {e0.x, e0.y, e0.z, e0.w, e1.x, e1.y, e1.z, e1.w};
            float EIm[8] = {f0.x, f0.y, f0.z, f0.w, f1.x, f1.y, f1.z, f1.w};
#pragma unroll
            for (int bb = 0; bb < 8; ++bb)
#pragma unroll
                for (int zz = 0; zz < 8; ++zz) {
                    acc[bb][zz] += PRe[bb] * ERe[zz] - PIm[bb] * EIm[zz];
                }
        }
    }

#pragma unroll
    for (int bb = 0; bb < 8; ++bb) {
        int b = bq * 8 + bb;
        size_t idx = (((size_t)cmh * B_N + b) * COUT + o) * T_N + zt * 128 + zq * 8;
        float4* p = (float4*)&partial[idx];
        p[0] = make_float4(acc[bb][0], acc[bb][1], acc[bb][2], acc[bb][3]);
        p[1] = make_float4(acc[bb][4], acc[bb][5], acc[bb][6], acc[bb][7]);
    }
}

// ---------------------------------------------------------------------------
// x2 reduce: outp += (1/N) * sum_{cmh} partial
// ---------------------------------------------------------------------------
__global__ __launch_bounds__(256) void k_x2red(const float4* __restrict__ p,
                                               float4* __restrict__ outp) {
    int f = blockIdx.x * 256 + threadIdx.x;      // 0..524287 float4
    const float inv_n = 1.0f / (float)T_N;
    float4 s = make_float4(0.f, 0.f, 0.f, 0.f);
#pragma unroll
    for (int c = 0; c < 4; ++c) {
        float4 v = p[(size_t)c * 524288 + f];
        s.x += v.x; s.y += v.y; s.z += v.z; s.w += v.w;
    }
    float4 o = outp[f];
    o.x += s.x * inv_n; o.y += s.y * inv_n; o.z += s.z * inv_n; o.w += s.w * inv_n;
    outp[f] = o;
}

// ---------------------------------------------------------------------------
extern "C" void kernel_launch(void* const* d_in, const int* in_sizes, int n_in,
                              void* d_out, int out_size, void* d_ws, size_t ws_size,
                              hipStream_t stream) {
    const float* x   = (const float*)d_in[0];
    const float* pr  = (const float*)d_in[2];
    const float* pim = (const float*)d_in[3];
    const float* rr  = (const float*)d_in[4];
    const float* ri  = (const float*)d_in[5];
    float* outp = (float*)d_out;

    char* ws = (char*)d_ws;
    const size_t MB = 1024 * 1024;
    float2* alpha   = (float2*)ws;                     // [0,16M)
    float2* alphaT  = (float2*)(ws + 16 * MB);         // [16M,32M)
    float2* o2      = (float2*)(ws + 32 * MB);         // [32M,32.25M)

    // out2 partial tier: xq:4 (32MB at 32.25M) if ws allows, else xq:2 (16MB, A)
    int xq_n;
    float2* o2part;
    if (ws_size >= (size_t)(65 * MB)) {
        xq_n = 4;
        o2part = (float2*)(ws + 32 * MB + 256 * 1024);
    } else {
        xq_n = 2;
        o2part = (float2*)ws;                          // region A (alpha dead)
    }
    float2* out1tmp = (float2*)ws;                     // region A (after reduce)
    float2* out1T   = (float2*)(ws + 16 * MB);         // region B (alphaT dead)
    float*  x2part  = (float*)ws;                      // [0,32M) (A+B dead)

    k_fft_fwd     <<<B_N * CIN, 256, 0, stream>>>(x, alpha);
    k_transpose_a <<<CIN * 32, 256, 0, stream>>>(alpha, alphaT);
    k_out2        <<<dim3(4, xq_n, 32), 256, 0, stream>>>((const float4*)alphaT,
                                                          pr, pim, rr, ri, o2part);
    k_reduce      <<<64, 256, 0, stream>>>((const float4*)o2part, (float4*)o2,
                                           32 * xq_n);
    k_out1        <<<T_N, 256, 0, stream>>>((const float4*)alphaT,
                                            pr, pim, rr, ri, out1tmp);
    k_transpose_o1<<<32 * 32, 256, 0, stream>>>(out1tmp, out1T);
    k_ifft        <<<B_N * COUT, 256, 0, stream>>>(out1T, outp);
    k_x2          <<<dim3(4, 8, 32), 128, 0, stream>>>((const float4*)o2,
                                                       pr, pim, x2part);
    k_x2red       <<<2048, 256, 0, stream>>>((const float4*)x2part, (float4*)outp);
}

// Round 12
// 221.434 us; speedup vs baseline: 1.4282x; 1.4282x over previous
//
#include <hip/hip_runtime.h>

#define T_N   1024
#define B_N   64
#define CIN   32
#define COUT  32
#define MODES 16
#define DT    0.01f
#define PI_F  3.14159265358979323846f
#define W_SCALE 0.613592315154256f   /* 2*pi/(T_N*DT) */
#define W_NYQ  (-314.1592653589793f) /* -pi/DT */

typedef short bf16x8 __attribute__((ext_vector_type(8)));
typedef float f32x4 __attribute__((ext_vector_type(4)));

__device__ __forceinline__ unsigned short f2bf_rn(float v) {
    unsigned int u = __float_as_uint(v);
    unsigned int rounded = u + 0x7FFFu + ((u >> 16) & 1u);
    return (unsigned short)(rounded >> 16);
}
__device__ __forceinline__ float bf2f(unsigned short s) {
    return __uint_as_float(((unsigned int)s) << 16);
}
__device__ __forceinline__ void bfsplit(float v, short* ph, short* pl) {
    unsigned short h = f2bf_rn(v);
    unsigned short lo = f2bf_rn(v - bf2f(h));
    *ph = (short)h; *pl = (short)lo;
}

// ---------------------------------------------------------------------------
// Radix-2 Stockham FFT, length 1024, LDS twiddle table.
// ---------------------------------------------------------------------------
template <int SIGN>
__device__ __forceinline__ void fft1024(float2* A, float2* B, const float2* TW, int tid) {
    float2* src = A;
    float2* dst = B;
    int m = 1;
#pragma unroll
    for (int s = 0; s < 10; ++s) {
        __syncthreads();
#pragma unroll
        for (int r = 0; r < 2; ++r) {
            int idx = tid + (r << 8);
            int k = idx & (m - 1);
            int j = idx >> s;
            float2 c0 = src[k + j * m];
            float2 c1 = src[k + j * m + 512];
            float2 w = TW[(j << s)];
            float ex = c0.x - c1.x, ey = c0.y - c1.y;
            dst[k + 2 * j * m]     = make_float2(c0.x + c1.x, c0.y + c1.y);
            dst[k + 2 * j * m + m] = make_float2(w.x * ex - w.y * ey, w.x * ey + w.y * ex);
        }
        float2* t = src; src = dst; dst = t;
        m <<= 1;
    }
    __syncthreads();
}

template <int SIGN>
__device__ __forceinline__ void build_tw(float2* TW, int tid) {
#pragma unroll
    for (int r = 0; r < 2; ++r) {
        int a = tid + (r << 8);
        float sn, cs;
        __sincosf((float)SIGN * PI_F * (float)a * (1.0f / 512.0f), &sn, &cs);
        TW[a] = make_float2(cs, sn);
    }
}

__global__ __launch_bounds__(256) void k_fft_fwd(const float* __restrict__ x,
                                                 float2* __restrict__ alpha) {
    __shared__ float2 A[1024];
    __shared__ float2 Bb[1024];
    __shared__ float2 TW[512];
    int row = blockIdx.x;
    int tid = threadIdx.x;
    build_tw<-1>(TW, tid);
    const float* xr = x + (size_t)row * T_N;
#pragma unroll
    for (int r = 0; r < 4; ++r) {
        int j = tid + (r << 8);
        A[j] = make_float2(xr[j], 0.0f);
    }
    fft1024<-1>(A, Bb, TW, tid);
    float2* outp = alpha + (size_t)row * T_N;
#pragma unroll
    for (int r = 0; r < 4; ++r) {
        int j = tid + (r << 8);
        outp[j] = A[j];
    }
}

// ---------------------------------------------------------------------------
// transpose alpha[(b*CIN+i)][x] -> alphaT[i][x][b]   (feeds k_out1 only now)
// ---------------------------------------------------------------------------
__global__ __launch_bounds__(256) void k_transpose_a(const float2* __restrict__ alpha,
                                                     float2* __restrict__ alphaT) {
    __shared__ float2 T[32 * 66];
    int blk = blockIdx.x;
    int i = blk >> 5, xt = blk & 31;
    int tid = threadIdx.x;
#pragma unroll
    for (int r = 0; r < 8; ++r) {
        int e = tid + (r << 8);
        int xx = e & 31, b = e >> 5;
        T[xx * 66 + b] = alpha[((size_t)(b * CIN + i)) * T_N + xt * 32 + xx];
    }
    __syncthreads();
#pragma unroll
    for (int r = 0; r < 8; ++r) {
        int e = tid + (r << 8);
        int b = e & 63, xx = e >> 6;
        alphaT[((size_t)i * T_N + xt * 32 + xx) * B_N + b] = T[xx * 66 + b];
    }
}

// ---------------------------------------------------------------------------
// conv: alpha row (b,i) -> split-bf16 A matrix  aBf[b][i][kappa], kappa=x*2+c
// x=0 column: imag slot carries Re(alpha[512]) (conjugate-fold pack).
// ---------------------------------------------------------------------------
__global__ __launch_bounds__(256) void k_conv(const float2* __restrict__ alpha,
                                              short* __restrict__ aHi,
                                              short* __restrict__ aLo) {
    int row = blockIdx.x;                 // b*CIN + i
    int tid = threadIdx.x;
    const float2* src = alpha + (size_t)row * T_N;
    size_t base = (size_t)row * 1024;
#pragma unroll
    for (int rr_ = 0; rr_ < 2; ++rr_) {
        int x = tid + (rr_ << 8);         // 0..511
        float2 v = src[x];
        float aR = v.x;
        float aI = (x == 0) ? src[512].x : v.y;
        short h0, l0, h1, l1;
        bfsplit(aR, &h0, &l0);
        bfsplit(aI, &h1, &l1);
        aHi[base + x * 2]     = h0;
        aHi[base + x * 2 + 1] = h1;
        aLo[base + x * 2]     = l0;
        aLo[base + x * 2 + 1] = l1;
    }
}

// ---------------------------------------------------------------------------
// out1: per-frequency mixing (unchanged — works).
// ---------------------------------------------------------------------------
__global__ __launch_bounds__(256) void k_out1(const float4* __restrict__ alphaT4,
                                              const float* __restrict__ pr,
                                              const float* __restrict__ pim,
                                              const float* __restrict__ rr,
                                              const float* __restrict__ ri,
                                              float2* __restrict__ out1tmp) {
    __shared__ float sARe[32 * 64];
    __shared__ float sAIm[32 * 64];
    __shared__ float2 Hs[32 * 32];
    int x = blockIdx.x;
    int tid = threadIdx.x;

#pragma unroll
    for (int r = 0; r < 4; ++r) {
        int e = tid + (r << 8);
        int i = e >> 5, bp = e & 31;
        float4 v = alphaT4[((size_t)i * T_N + x) * (B_N / 2) + bp];
        *(float2*)&sARe[i * 64 + bp * 2] = make_float2(v.x, v.z);
        *(float2*)&sAIm[i * 64 + bp * 2] = make_float2(v.y, v.w);
    }

    int fx = x - ((x >= 512) ? 1024 : 0);
    float w = (float)fx * W_SCALE;
#pragma unroll
    for (int r = 0; r < 4; ++r) {
        int e = tid + (r << 8);
        int i = e >> 5, o = e & 31;
        int base = (i * COUT + o) * MODES;
        float hr = 0.f, hi = 0.f;
#pragma unroll
        for (int k = 0; k < MODES; ++k) {
            float a = pr[base + k], bI = pim[base + k];
            float d = w - bI;
            float inv = 1.0f / (a * a + d * d);
            float vR = -a * inv, vI = -d * inv;
            float sR = rr[base + k], sI = ri[base + k];
            hr += sR * vR - sI * vI;
            hi += sR * vI + sI * vR;
        }
        Hs[i * 32 + o] = make_float2(hr, hi);
    }
    __syncthreads();

    int o = tid & 31, bg = tid >> 5;
    float accR[8] = {}, accI[8] = {};
#pragma unroll 2
    for (int i = 0; i < CIN; ++i) {
        float2 h = Hs[i * 32 + o];
        float4 ar0 = *(const float4*)&sARe[i * 64 + bg * 8];
        float4 ar1 = *(const float4*)&sARe[i * 64 + bg * 8 + 4];
        float4 ai0 = *(const float4*)&sAIm[i * 64 + bg * 8];
        float4 ai1 = *(const float4*)&sAIm[i * 64 + bg * 8 + 4];
        float aR[8] = {ar0.x, ar0.y, ar0.z, ar0.w, ar1.x, ar1.y, ar1.z, ar1.w};
        float aI[8] = {ai0.x, ai0.y, ai0.z, ai0.w, ai1.x, ai1.y, ai1.z, ai1.w};
#pragma unroll
        for (int bb = 0; bb < 8; ++bb) {
            accR[bb] += aR[bb] * h.x - aI[bb] * h.y;
            accI[bb] += aR[bb] * h.y + aI[bb] * h.x;
        }
    }
#pragma unroll
    for (int bb = 0; bb < 8; ++bb) {
        out1tmp[(size_t)x * 2048 + (bg * 8 + bb) * 32 + o] =
            make_float2(accR[bb], accI[bb]);
    }
}

// ---------------------------------------------------------------------------
// out2 MFMA: out2[b,n] = sum_kappa A[b,kappa]*B[kappa,n], split-bf16 (3 prod).
// n = (o*16+k)*2 + {R,I}; kappa = x*2 + {aR,aI} within (i,xh) K-slice of 512.
// Grid dim3(nb:16, xh:2, i:32), 256 thr = 4 waves; wave w owns n-cols
// [nb*64+w*16, +16); 4 M-tiles of 16 b. B built per K-step in LDS (hi/lo).
// Slot-symmetric A/B loads -> k-permutation cancels; C/D layout per m89.
// partial[chunk=(i*2+xh)][b][n] fp32, 64 chunks x 256KB.
// ---------------------------------------------------------------------------
#define ABROW 40   /* shorts per LDS row: 32 data + 8 pad (80B, 16B-aligned) */
__global__ __launch_bounds__(256) void k_out2m(const short* __restrict__ aHi,
                                               const short* __restrict__ aLo,
                                               const float* __restrict__ pr,
                                               const float* __restrict__ pim,
                                               const float* __restrict__ rr,
                                               const float* __restrict__ ri,
                                               float* __restrict__ partial) {
    __shared__ short sAh[64 * ABROW], sAl[64 * ABROW];
    __shared__ short sBh[64 * ABROW], sBl[64 * ABROW];
    __shared__ float sPol[4][32];

    const int nb = blockIdx.x, xh = blockIdx.y, i = blockIdx.z;
    const int tid = threadIdx.x;
    const int w = tid >> 6, l = tid & 63;
    const int r = l & 15, hg = l >> 4;

    if (tid < 32) {
        int o = nb * 2 + (tid >> 4), k = tid & 15;
        int pidx = (i * COUT + o) * MODES + k;
        sPol[0][tid] = pr[pidx]; sPol[1][tid] = pim[pidx];
        sPol[2][tid] = rr[pidx]; sPol[3][tid] = ri[pidx];
    }
    __syncthreads();

    f32x4 acc0 = {0.f, 0.f, 0.f, 0.f};
    f32x4 acc1 = {0.f, 0.f, 0.f, 0.f};
    f32x4 acc2 = {0.f, 0.f, 0.f, 0.f};
    f32x4 acc3 = {0.f, 0.f, 0.f, 0.f};

    const int sb = tid >> 2;                 // staging row (b)
    const int sc = (tid & 3) * 8;            // staging col (shorts)
    const size_t abase = ((size_t)sb * CIN + i) * 1024 + (size_t)xh * 512;

    for (int ks = 0; ks < 16; ++ks) {
        __syncthreads();
        // stage A tile (hi & lo): 64 b x 32 kappa
        *(float4*)&sAh[sb * ABROW + sc] = *(const float4*)&aHi[abase + ks * 32 + sc];
        *(float4*)&sAl[sb * ABROW + sc] = *(const float4*)&aLo[abase + ks * 32 + sc];
        // build B tile: 512 quads (16 x * 32 ok), 2 per thread
#pragma unroll
        for (int qq = 0; qq < 2; ++qq) {
            int q = tid * 2 + qq;
            int xl = q >> 5, ok = q & 31;
            int xg = xh * 256 + ks * 16 + xl;
            float a = sPol[0][ok], bI = sPol[1][ok];
            float sR = sPol[2][ok], sI = sPol[3][ok];
            float c1r, c1i, c2r, c2i;
            if (xg == 0) {
                float s1 = a * a + bI * bI;
                float q1r = a / s1, q1i = -bI / s1;
                c1r = sR * q1r - sI * q1i;
                c1i = sR * q1i + sI * q1r;
                float dr = -a, di = W_NYQ - bI;
                float s2 = dr * dr + di * di;
                float q2r = dr / s2, q2i = -di / s2;
                c2r = -(sR * q2r - sI * q2i);
                c2i = -(sR * q2i + sI * q2r);
            } else {
                float wv = (float)xg * W_SCALE;
                float denr = a * a - bI * bI + wv * wv;
                float deni = 2.0f * a * bI;
                float s = denr * denr + deni * deni;
                float qr = denr / s, qi = -deni / s;
                float prr = a * sR - bI * sI;
                float pri = a * sI + bI * sR;
                c1r = 2.0f * (prr * qr - pri * qi);
                c1i = 2.0f * (prr * qi + pri * qr);
                float rqr = sR * qr - sI * qi;
                float rqi = sR * qi + sI * qr;
                c2r = -2.0f * wv * rqr;
                c2i = -2.0f * wv * rqi;
            }
            int n0 = (ok * 2) * ABROW, n1 = (ok * 2 + 1) * ABROW;
            int c0 = xl * 2, c1c = xl * 2 + 1;
            bfsplit(c1r, &sBh[n0 + c0],  &sBl[n0 + c0]);
            bfsplit(c2r, &sBh[n0 + c1c], &sBl[n0 + c1c]);
            bfsplit(c1i, &sBh[n1 + c0],  &sBl[n1 + c0]);
            bfsplit(c2i, &sBh[n1 + c1c], &sBl[n1 + c1c]);
        }
        __syncthreads();

        // MFMA: wave's B frag + 4 M-tile A frags, 3 split products each
        bf16x8 bh = *(bf16x8*)&sBh[(w * 16 + r) * ABROW + hg * 8];
        bf16x8 bl = *(bf16x8*)&sBl[(w * 16 + r) * ABROW + hg * 8];
        {
            bf16x8 ah = *(bf16x8*)&sAh[(0 * 16 + r) * ABROW + hg * 8];
            bf16x8 al = *(bf16x8*)&sAl[(0 * 16 + r) * ABROW + hg * 8];
            acc0 = __builtin_amdgcn_mfma_f32_16x16x32_bf16(ah, bh, acc0, 0, 0, 0);
            acc0 = __builtin_amdgcn_mfma_f32_16x16x32_bf16(al, bh, acc0, 0, 0, 0);
            acc0 = __builtin_amdgcn_mfma_f32_16x16x32_bf16(ah, bl, acc0, 0, 0, 0);
        }
        {
            bf16x8 ah = *(bf16x8*)&sAh[(1 * 16 + r) * ABROW + hg * 8];
            bf16x8 al = *(bf16x8*)&sAl[(1 * 16 + r) * ABROW + hg * 8];
            acc1 = __builtin_amdgcn_mfma_f32_16x16x32_bf16(ah, bh, acc1, 0, 0, 0);
            acc1 = __builtin_amdgcn_mfma_f32_16x16x32_bf16(al, bh, acc1, 0, 0, 0);
            acc1 = __builtin_amdgcn_mfma_f32_16x16x32_bf16(ah, bl, acc1, 0, 0, 0);
        }
        {
            bf16x8 ah = *(bf16x8*)&sAh[(2 * 16 + r) * ABROW + hg * 8];
            bf16x8 al = *(bf16x8*)&sAl[(2 * 16 + r) * ABROW + hg * 8];
            acc2 = __builtin_amdgcn_mfma_f32_16x16x32_bf16(ah, bh, acc2, 0, 0, 0);
            acc2 = __builtin_amdgcn_mfma_f32_16x16x32_bf16(al, bh, acc2, 0, 0, 0);
            acc2 = __builtin_amdgcn_mfma_f32_16x16x32_bf16(ah, bl, acc2, 0, 0, 0);
        }
        {
            bf16x8 ah = *(bf16x8*)&sAh[(3 * 16 + r) * ABROW + hg * 8];
            bf16x8 al = *(bf16x8*)&sAl[(3 * 16 + r) * ABROW + hg * 8];
            acc3 = __builtin_amdgcn_mfma_f32_16x16x32_bf16(ah, bh, acc3, 0, 0, 0);
            acc3 = __builtin_amdgcn_mfma_f32_16x16x32_bf16(al, bh, acc3, 0, 0, 0);
            acc3 = __builtin_amdgcn_mfma_f32_16x16x32_bf16(ah, bl, acc3, 0, 0, 0);
        }
    }

    // epilogue: C/D layout col=lane&15 (n), row=(lane>>4)*4+reg (b)
    int chunk = i * 2 + xh;
    int n = nb * 64 + w * 16 + r;
    float* dst = partial + (size_t)chunk * (B_N * 1024) + n;
#pragma unroll
    for (int reg = 0; reg < 4; ++reg) {
        dst[(0 * 16 + hg * 4 + reg) * 1024] = acc0[reg];
        dst[(1 * 16 + hg * 4 + reg) * 1024] = acc1[reg];
        dst[(2 * 16 + hg * 4 + reg) * 1024] = acc2[reg];
        dst[(3 * 16 + hg * 4 + reg) * 1024] = acc3[reg];
    }
}

// ---------------------------------------------------------------------------
// reduce nchunk partials into o2[b][n]  (n = (o,k) float2 pairs)
// ---------------------------------------------------------------------------
__global__ __launch_bounds__(256) void k_reduce(const float4* __restrict__ p,
                                                float4* __restrict__ o2, int nchunk) {
    int f = blockIdx.x * 256 + threadIdx.x;   // 16384 float4s
    float4 s = make_float4(0.f, 0.f, 0.f, 0.f);
    for (int c = 0; c < nchunk; ++c) {
        float4 v = p[(size_t)c * 16384 + f];
        s.x += v.x; s.y += v.y; s.z += v.z; s.w += v.w;
    }
    o2[f] = s;
}

// ---------------------------------------------------------------------------
// transpose out1tmp[x][bo] -> out1T[bo][x]
// ---------------------------------------------------------------------------
__global__ __launch_bounds__(256) void k_transpose_o1(const float2* __restrict__ out1tmp,
                                                      float2* __restrict__ out1T) {
    __shared__ float2 T[64 * 33];
    int blk = blockIdx.x;
    int bot = blk >> 5, xt = blk & 31;
    int tid = threadIdx.x;
#pragma unroll
    for (int r = 0; r < 8; ++r) {
        int e = tid + (r << 8);
        int j = e & 63, xr = e >> 6;
        T[j * 33 + xr] = out1tmp[((size_t)(xt * 32 + xr)) * 2048 + bot * 64 + j];
    }
    __syncthreads();
#pragma unroll
    for (int r = 0; r < 8; ++r) {
        int e = tid + (r << 8);
        int xx = e & 31, j = e >> 5;
        out1T[((size_t)(bot * 64 + j)) * T_N + xt * 32 + xx] = T[j * 33 + xx];
    }
}

__global__ __launch_bounds__(256) void k_ifft(const float2* __restrict__ out1T,
                                              float* __restrict__ outp) {
    __shared__ float2 A[1024];
    __shared__ float2 Bb[1024];
    __shared__ float2 TW[512];
    int row = blockIdx.x;
    int tid = threadIdx.x;
    build_tw<1>(TW, tid);
    const float2* src = out1T + (size_t)row * T_N;
#pragma unroll
    for (int r = 0; r < 4; ++r) {
        int j = tid + (r << 8);
        A[j] = src[j];
    }
    fft1024<1>(A, Bb, TW, tid);
    float* dst = outp + (size_t)row * T_N;
    const float inv_n = 1.0f / (float)T_N;
#pragma unroll
    for (int r = 0; r < 4; ++r) {
        int j = tid + (r << 8);
        dst[j] = A[j].x * inv_n;
    }
}

// ---------------------------------------------------------------------------
// x2 (R10 proven): grid dim3(cmh:4, zt:8, o:32), 256 thr, 8b x 4z acc.
// ---------------------------------------------------------------------------
#define PROW 100
#define EROW 132
__global__ __launch_bounds__(256) void k_x2(const float4* __restrict__ o2f4,
                                            const float* __restrict__ pr,
                                            const float* __restrict__ pim,
                                            float* __restrict__ partial) {
    __shared__ __align__(16) float sPre[16 * PROW], sPim_[16 * PROW];
    __shared__ __align__(16) float sEre[16 * EROW], sEim[16 * EROW];
    __shared__ float s_pr[128], s_pim[128];

    const int cmh = blockIdx.x, zt = blockIdx.y, o = blockIdx.z;
    const int tid = threadIdx.x;
    const int zq = tid & 31, bq = tid >> 5;
    const int cmBase = cmh * 128;

    if (tid < 128) {
        int cm = cmBase + tid;
        int c = cm >> 4, m = cm & 15;
        int pidx = (c * COUT + o) * MODES + m;
        s_pr[tid] = pr[pidx];
        s_pim[tid] = pim[pidx];
    }

    float acc[8][4] = {};

    for (int t = 0; t < 8; ++t) {
        int cm0l = t * 16;
        __syncthreads();
#pragma unroll
        for (int r = 0; r < 2; ++r) {
            int e = tid + (r << 8);              // 0..511: b=e>>3, jp=e&7
            int b = e >> 3, jp = e & 7;
            float4 v = o2f4[b * 256 + ((cmBase + cm0l) >> 1) + jp];
            int j0 = jp * 2;
            int pa = (b >> 3) * 12 + (b & 7);
            sPre[j0 * PROW + pa] = v.x;
            sPim_[j0 * PROW + pa] = v.y;
            sPre[(j0 + 1) * PROW + pa] = v.z;
            sPim_[(j0 + 1) * PROW + pa] = v.w;
        }
#pragma unroll
        for (int r = 0; r < 8; ++r) {
            int e = tid + (r << 8);
            int z = e & 127, j = e >> 7;
            float gr = s_pr[cm0l + j], gi = s_pim[cm0l + j];
            float tz = (float)(zt * 128 + z) * DT;
            float er = __expf(gr * tz);
            float sn, cn;
            __sincosf(gi * tz, &sn, &cn);
            sEre[j * EROW + z] = er * cn;
            sEim[j * EROW + z] = er * sn;
        }
        __syncthreads();

#pragma unroll 4
        for (int j = 0; j < 16; ++j) {
            const float* pp = &sPre[j * PROW + bq * 12];
            const float* qq = &sPim_[j * PROW + bq * 12];
            float4 p0 = *(const float4*)&pp[0];
            float4 p1 = *(const float4*)&pp[4];
            float4 q0 = *(const float4*)&qq[0];
            float4 q1 = *(const float4*)&qq[4];
            float4 e0 = *(const float4*)&sEre[j * EROW + zq * 4];
            float4 e1 = *(const float4*)&sEim[j * EROW + zq * 4];
            float PRe[8] = {p0.x, p0.y, p0.z, p0.w, p1.x, p1.y, p1.z, p1.w};
            float PIm[8] = {q0.x, q0.y, q0.z, q0.w, q1.x, q1.y, q1.z, q1.w};
            float ERe[4] = {e0.x, e0.y, e0.z, e0.w};
            float EIm[4] = {e1.x, e1.y, e1.z, e1.w};
#pragma unroll
            for (int bb = 0; bb < 8; ++bb)
#pragma unroll
                for (int zz = 0; zz < 4; ++zz) {
                    acc[bb][zz] += PRe[bb] * ERe[zz] - PIm[bb] * EIm[zz];
                }
        }
    }

#pragma unroll
    for (int bb = 0; bb < 8; ++bb) {
        int b = bq * 8 + bb;
        size_t idx = (((size_t)cmh * B_N + b) * COUT + o) * T_N + zt * 128 + zq * 4;
        *(float4*)&partial[idx] = make_float4(acc[bb][0], acc[bb][1], acc[bb][2], acc[bb][3]);
    }
}

// ---------------------------------------------------------------------------
// x2 reduce: outp += (1/N) * sum_{cmh} partial
// ---------------------------------------------------------------------------
__global__ __launch_bounds__(256) void k_x2red(const float4* __restrict__ p,
                                               float4* __restrict__ outp) {
    int f = blockIdx.x * 256 + threadIdx.x;      // 0..524287 float4
    const float inv_n = 1.0f / (float)T_N;
    float4 s = make_float4(0.f, 0.f, 0.f, 0.f);
#pragma unroll
    for (int c = 0; c < 4; ++c) {
        float4 v = p[(size_t)c * 524288 + f];
        s.x += v.x; s.y += v.y; s.z += v.z; s.w += v.w;
    }
    float4 o = outp[f];
    o.x += s.x * inv_n; o.y += s.y * inv_n; o.z += s.z * inv_n; o.w += s.w * inv_n;
    outp[f] = o;
}

// ---------------------------------------------------------------------------
extern "C" void kernel_launch(void* const* d_in, const int* in_sizes, int n_in,
                              void* d_out, int out_size, void* d_ws, size_t ws_size,
                              hipStream_t stream) {
    const float* x   = (const float*)d_in[0];
    const float* pr  = (const float*)d_in[2];
    const float* pim = (const float*)d_in[3];
    const float* rr  = (const float*)d_in[4];
    const float* ri  = (const float*)d_in[5];
    float* outp = (float*)d_out;

    char* ws = (char*)d_ws;
    const size_t MB = 1024 * 1024;
    float2* alpha   = (float2*)ws;                     // [0,16M)
    float2* alphaT  = (float2*)(ws + 16 * MB);         // [16M,32M)
    float2* o2      = (float2*)(ws + 32 * MB);         // [32M,32.25M)
    short*  aHi     = (short*)(ws + 33 * MB);          // [33M,37M)
    short*  aLo     = (short*)(ws + 37 * MB);          // [37M,41M)
    float*  o2part;
    if (ws_size >= (size_t)(57 * MB)) {
        o2part = (float*)(ws + 41 * MB);               // [41M,57M): 64 x 256KB
    } else {
        o2part = (float*)ws;                           // region A (alpha dead)
    }
    float2* out1tmp = (float2*)ws;                     // region A (after reduce)
    float2* out1T   = (float2*)(ws + 16 * MB);         // region B (alphaT dead)
    float*  x2part  = (float*)ws;                      // [0,32M) (A+B dead)

    k_fft_fwd     <<<B_N * CIN, 256, 0, stream>>>(x, alpha);
    k_transpose_a <<<CIN * 32, 256, 0, stream>>>(alpha, alphaT);
    k_conv        <<<B_N * CIN, 256, 0, stream>>>(alpha, aHi, aLo);
    k_out2m       <<<dim3(16, 2, 32), 256, 0, stream>>>(aHi, aLo,
                                                        pr, pim, rr, ri, o2part);
    k_reduce      <<<64, 256, 0, stream>>>((const float4*)o2part, (float4*)o2, 64);
    k_out1        <<<T_N, 256, 0, stream>>>((const float4*)alphaT,
                                            pr, pim, rr, ri, out1tmp);
    k_transpose_o1<<<32 * 32, 256, 0, stream>>>(out1tmp, out1T);
    k_ifft        <<<B_N * COUT, 256, 0, stream>>>(out1T, outp);
    k_x2          <<<dim3(4, 8, 32), 256, 0, stream>>>((const float4*)o2,
                                                       pr, pim, x2part);
    k_x2red       <<<2048, 256, 0, stream>>>((const float4*)x2part, (float4*)outp);
}

// Round 13
// 167.372 us; speedup vs baseline: 1.8895x; 1.3230x over previous
//
#include <hip/hip_runtime.h>

#define T_N   1024
#define B_N   64
#define CIN   32
#define COUT  32
#define MODES 16
#define DT    0.01f
#define PI_F  3.14159265358979323846f
#define W_SCALE 0.613592315154256f   /* 2*pi/(T_N*DT) */
#define W_NYQ  (-314.1592653589793f) /* -pi/DT */

typedef short bf16x8 __attribute__((ext_vector_type(8)));
typedef float f32x4 __attribute__((ext_vector_type(4)));

__device__ __forceinline__ unsigned short f2bf_rn(float v) {
    unsigned int u = __float_as_uint(v);
    unsigned int rounded = u + 0x7FFFu + ((u >> 16) & 1u);
    return (unsigned short)(rounded >> 16);
}
__device__ __forceinline__ float bf2f(unsigned short s) {
    return __uint_as_float(((unsigned int)s) << 16);
}
__device__ __forceinline__ void bfsplit(float v, short* ph, short* pl) {
    unsigned short h = f2bf_rn(v);
    unsigned short lo = f2bf_rn(v - bf2f(h));
    *ph = (short)h; *pl = (short)lo;
}

// ---------------------------------------------------------------------------
// Radix-2 Stockham FFT, length 1024, LDS twiddle table.
// ---------------------------------------------------------------------------
template <int SIGN>
__device__ __forceinline__ void fft1024(float2* A, float2* B, const float2* TW, int tid) {
    float2* src = A;
    float2* dst = B;
    int m = 1;
#pragma unroll
    for (int s = 0; s < 10; ++s) {
        __syncthreads();
#pragma unroll
        for (int r = 0; r < 2; ++r) {
            int idx = tid + (r << 8);
            int k = idx & (m - 1);
            int j = idx >> s;
            float2 c0 = src[k + j * m];
            float2 c1 = src[k + j * m + 512];
            float2 w = TW[(j << s)];
            float ex = c0.x - c1.x, ey = c0.y - c1.y;
            dst[k + 2 * j * m]     = make_float2(c0.x + c1.x, c0.y + c1.y);
            dst[k + 2 * j * m + m] = make_float2(w.x * ex - w.y * ey, w.x * ey + w.y * ex);
        }
        float2* t = src; src = dst; dst = t;
        m <<= 1;
    }
    __syncthreads();
}

template <int SIGN>
__device__ __forceinline__ void build_tw(float2* TW, int tid) {
#pragma unroll
    for (int r = 0; r < 2; ++r) {
        int a = tid + (r << 8);
        float sn, cs;
        __sincosf((float)SIGN * PI_F * (float)a * (1.0f / 512.0f), &sn, &cs);
        TW[a] = make_float2(cs, sn);
    }
}

__global__ __launch_bounds__(256) void k_fft_fwd(const float* __restrict__ x,
                                                 float2* __restrict__ alpha) {
    __shared__ float2 A[1024];
    __shared__ float2 Bb[1024];
    __shared__ float2 TW[512];
    int row = blockIdx.x;
    int tid = threadIdx.x;
    build_tw<-1>(TW, tid);
    const float* xr = x + (size_t)row * T_N;
#pragma unroll
    for (int r = 0; r < 4; ++r) {
        int j = tid + (r << 8);
        A[j] = make_float2(xr[j], 0.0f);
    }
    fft1024<-1>(A, Bb, TW, tid);
    float2* outp = alpha + (size_t)row * T_N;
#pragma unroll
    for (int r = 0; r < 4; ++r) {
        int j = tid + (r << 8);
        outp[j] = A[j];
    }
}

// ---------------------------------------------------------------------------
// transpose alpha[(b*CIN+i)][x] -> alphaT[i][x][b]   (feeds k_out1 only)
// ---------------------------------------------------------------------------
__global__ __launch_bounds__(256) void k_transpose_a(const float2* __restrict__ alpha,
                                                     float2* __restrict__ alphaT) {
    __shared__ float2 T[32 * 66];
    int blk = blockIdx.x;
    int i = blk >> 5, xt = blk & 31;
    int tid = threadIdx.x;
#pragma unroll
    for (int r = 0; r < 8; ++r) {
        int e = tid + (r << 8);
        int xx = e & 31, b = e >> 5;
        T[xx * 66 + b] = alpha[((size_t)(b * CIN + i)) * T_N + xt * 32 + xx];
    }
    __syncthreads();
#pragma unroll
    for (int r = 0; r < 8; ++r) {
        int e = tid + (r << 8);
        int b = e & 63, xx = e >> 6;
        alphaT[((size_t)i * T_N + xt * 32 + xx) * B_N + b] = T[xx * 66 + b];
    }
}

// ---------------------------------------------------------------------------
// conv: alpha row (b,i) -> split-bf16 A matrix  aBf[b][i][kappa], kappa=x*2+c
// x=0 column: imag slot carries Re(alpha[512]) (conjugate-fold pack).
// ---------------------------------------------------------------------------
__global__ __launch_bounds__(256) void k_conv(const float2* __restrict__ alpha,
                                              short* __restrict__ aHi,
                                              short* __restrict__ aLo) {
    int row = blockIdx.x;                 // b*CIN + i
    int tid = threadIdx.x;
    const float2* src = alpha + (size_t)row * T_N;
    size_t base = (size_t)row * 1024;
#pragma unroll
    for (int rr_ = 0; rr_ < 2; ++rr_) {
        int x = tid + (rr_ << 8);         // 0..511
        float2 v = src[x];
        float aR = v.x;
        float aI = (x == 0) ? src[512].x : v.y;
        short h0, l0, h1, l1;
        bfsplit(aR, &h0, &l0);
        bfsplit(aI, &h1, &l1);
        aHi[base + x * 2]     = h0;
        aHi[base + x * 2 + 1] = h1;
        aLo[base + x * 2]     = l0;
        aLo[base + x * 2 + 1] = l1;
    }
}

// ---------------------------------------------------------------------------
// out1: per-frequency mixing (unchanged — works).
// ---------------------------------------------------------------------------
__global__ __launch_bounds__(256) void k_out1(const float4* __restrict__ alphaT4,
                                              const float* __restrict__ pr,
                                              const float* __restrict__ pim,
                                              const float* __restrict__ rr,
                                              const float* __restrict__ ri,
                                              float2* __restrict__ out1tmp) {
    __shared__ float sARe[32 * 64];
    __shared__ float sAIm[32 * 64];
    __shared__ float2 Hs[32 * 32];
    int x = blockIdx.x;
    int tid = threadIdx.x;

#pragma unroll
    for (int r = 0; r < 4; ++r) {
        int e = tid + (r << 8);
        int i = e >> 5, bp = e & 31;
        float4 v = alphaT4[((size_t)i * T_N + x) * (B_N / 2) + bp];
        *(float2*)&sARe[i * 64 + bp * 2] = make_float2(v.x, v.z);
        *(float2*)&sAIm[i * 64 + bp * 2] = make_float2(v.y, v.w);
    }

    int fx = x - ((x >= 512) ? 1024 : 0);
    float w = (float)fx * W_SCALE;
#pragma unroll
    for (int r = 0; r < 4; ++r) {
        int e = tid + (r << 8);
        int i = e >> 5, o = e & 31;
        int base = (i * COUT + o) * MODES;
        float hr = 0.f, hi = 0.f;
#pragma unroll
        for (int k = 0; k < MODES; ++k) {
            float a = pr[base + k], bI = pim[base + k];
            float d = w - bI;
            float inv = 1.0f / (a * a + d * d);
            float vR = -a * inv, vI = -d * inv;
            float sR = rr[base + k], sI = ri[base + k];
            hr += sR * vR - sI * vI;
            hi += sR * vI + sI * vR;
        }
        Hs[i * 32 + o] = make_float2(hr, hi);
    }
    __syncthreads();

    int o = tid & 31, bg = tid >> 5;
    float accR[8] = {}, accI[8] = {};
#pragma unroll 2
    for (int i = 0; i < CIN; ++i) {
        float2 h = Hs[i * 32 + o];
        float4 ar0 = *(const float4*)&sARe[i * 64 + bg * 8];
        float4 ar1 = *(const float4*)&sARe[i * 64 + bg * 8 + 4];
        float4 ai0 = *(const float4*)&sAIm[i * 64 + bg * 8];
        float4 ai1 = *(const float4*)&sAIm[i * 64 + bg * 8 + 4];
        float aR[8] = {ar0.x, ar0.y, ar0.z, ar0.w, ar1.x, ar1.y, ar1.z, ar1.w};
        float aI[8] = {ai0.x, ai0.y, ai0.z, ai0.w, ai1.x, ai1.y, ai1.z, ai1.w};
#pragma unroll
        for (int bb = 0; bb < 8; ++bb) {
            accR[bb] += aR[bb] * h.x - aI[bb] * h.y;
            accI[bb] += aR[bb] * h.y + aI[bb] * h.x;
        }
    }
#pragma unroll
    for (int bb = 0; bb < 8; ++bb) {
        out1tmp[(size_t)x * 2048 + (bg * 8 + bb) * 32 + o] =
            make_float2(accR[bb], accI[bb]);
    }
}

// ---------------------------------------------------------------------------
// out2 MFMA (proven R12): partial[chunk=(i*2+xh)][b][n] fp32, 64 chunks.
// ---------------------------------------------------------------------------
#define ABROW 40   /* shorts per LDS row: 32 data + 8 pad (80B, 16B-aligned) */
__global__ __launch_bounds__(256) void k_out2m(const short* __restrict__ aHi,
                                               const short* __restrict__ aLo,
                                               const float* __restrict__ pr,
                                               const float* __restrict__ pim,
                                               const float* __restrict__ rr,
                                               const float* __restrict__ ri,
                                               float* __restrict__ partial) {
    __shared__ short sAh[64 * ABROW], sAl[64 * ABROW];
    __shared__ short sBh[64 * ABROW], sBl[64 * ABROW];
    __shared__ float sPol[4][32];

    const int nb = blockIdx.x, xh = blockIdx.y, i = blockIdx.z;
    const int tid = threadIdx.x;
    const int w = tid >> 6, l = tid & 63;
    const int r = l & 15, hg = l >> 4;

    if (tid < 32) {
        int o = nb * 2 + (tid >> 4), k = tid & 15;
        int pidx = (i * COUT + o) * MODES + k;
        sPol[0][tid] = pr[pidx]; sPol[1][tid] = pim[pidx];
        sPol[2][tid] = rr[pidx]; sPol[3][tid] = ri[pidx];
    }
    __syncthreads();

    f32x4 acc0 = {0.f, 0.f, 0.f, 0.f};
    f32x4 acc1 = {0.f, 0.f, 0.f, 0.f};
    f32x4 acc2 = {0.f, 0.f, 0.f, 0.f};
    f32x4 acc3 = {0.f, 0.f, 0.f, 0.f};

    const int sb = tid >> 2;                 // staging row (b)
    const int sc = (tid & 3) * 8;            // staging col (shorts)
    const size_t abase = ((size_t)sb * CIN + i) * 1024 + (size_t)xh * 512;

    for (int ks = 0; ks < 16; ++ks) {
        __syncthreads();
        *(float4*)&sAh[sb * ABROW + sc] = *(const float4*)&aHi[abase + ks * 32 + sc];
        *(float4*)&sAl[sb * ABROW + sc] = *(const float4*)&aLo[abase + ks * 32 + sc];
#pragma unroll
        for (int qq = 0; qq < 2; ++qq) {
            int q = tid * 2 + qq;
            int xl = q >> 5, ok = q & 31;
            int xg = xh * 256 + ks * 16 + xl;
            float a = sPol[0][ok], bI = sPol[1][ok];
            float sR = sPol[2][ok], sI = sPol[3][ok];
            float c1r, c1i, c2r, c2i;
            if (xg == 0) {
                float s1 = a * a + bI * bI;
                float q1r = a / s1, q1i = -bI / s1;
                c1r = sR * q1r - sI * q1i;
                c1i = sR * q1i + sI * q1r;
                float dr = -a, di = W_NYQ - bI;
                float s2 = dr * dr + di * di;
                float q2r = dr / s2, q2i = -di / s2;
                c2r = -(sR * q2r - sI * q2i);
                c2i = -(sR * q2i + sI * q2r);
            } else {
                float wv = (float)xg * W_SCALE;
                float denr = a * a - bI * bI + wv * wv;
                float deni = 2.0f * a * bI;
                float s = denr * denr + deni * deni;
                float qr = denr / s, qi = -deni / s;
                float prr = a * sR - bI * sI;
                float pri = a * sI + bI * sR;
                c1r = 2.0f * (prr * qr - pri * qi);
                c1i = 2.0f * (prr * qi + pri * qr);
                float rqr = sR * qr - sI * qi;
                float rqi = sR * qi + sI * qr;
                c2r = -2.0f * wv * rqr;
                c2i = -2.0f * wv * rqi;
            }
            int n0 = (ok * 2) * ABROW, n1 = (ok * 2 + 1) * ABROW;
            int c0 = xl * 2, c1c = xl * 2 + 1;
            bfsplit(c1r, &sBh[n0 + c0],  &sBl[n0 + c0]);
            bfsplit(c2r, &sBh[n0 + c1c], &sBl[n0 + c1c]);
            bfsplit(c1i, &sBh[n1 + c0],  &sBl[n1 + c0]);
            bfsplit(c2i, &sBh[n1 + c1c], &sBl[n1 + c1c]);
        }
        __syncthreads();

        bf16x8 bh = *(bf16x8*)&sBh[(w * 16 + r) * ABROW + hg * 8];
        bf16x8 bl = *(bf16x8*)&sBl[(w * 16 + r) * ABROW + hg * 8];
        {
            bf16x8 ah = *(bf16x8*)&sAh[(0 * 16 + r) * ABROW + hg * 8];
            bf16x8 al = *(bf16x8*)&sAl[(0 * 16 + r) * ABROW + hg * 8];
            acc0 = __builtin_amdgcn_mfma_f32_16x16x32_bf16(ah, bh, acc0, 0, 0, 0);
            acc0 = __builtin_amdgcn_mfma_f32_16x16x32_bf16(al, bh, acc0, 0, 0, 0);
            acc0 = __builtin_amdgcn_mfma_f32_16x16x32_bf16(ah, bl, acc0, 0, 0, 0);
        }
        {
            bf16x8 ah = *(bf16x8*)&sAh[(1 * 16 + r) * ABROW + hg * 8];
            bf16x8 al = *(bf16x8*)&sAl[(1 * 16 + r) * ABROW + hg * 8];
            acc1 = __builtin_amdgcn_mfma_f32_16x16x32_bf16(ah, bh, acc1, 0, 0, 0);
            acc1 = __builtin_amdgcn_mfma_f32_16x16x32_bf16(al, bh, acc1, 0, 0, 0);
            acc1 = __builtin_amdgcn_mfma_f32_16x16x32_bf16(ah, bl, acc1, 0, 0, 0);
        }
        {
            bf16x8 ah = *(bf16x8*)&sAh[(2 * 16 + r) * ABROW + hg * 8];
            bf16x8 al = *(bf16x8*)&sAl[(2 * 16 + r) * ABROW + hg * 8];
            acc2 = __builtin_amdgcn_mfma_f32_16x16x32_bf16(ah, bh, acc2, 0, 0, 0);
            acc2 = __builtin_amdgcn_mfma_f32_16x16x32_bf16(al, bh, acc2, 0, 0, 0);
            acc2 = __builtin_amdgcn_mfma_f32_16x16x32_bf16(ah, bl, acc2, 0, 0, 0);
        }
        {
            bf16x8 ah = *(bf16x8*)&sAh[(3 * 16 + r) * ABROW + hg * 8];
            bf16x8 al = *(bf16x8*)&sAl[(3 * 16 + r) * ABROW + hg * 8];
            acc3 = __builtin_amdgcn_mfma_f32_16x16x32_bf16(ah, bh, acc3, 0, 0, 0);
            acc3 = __builtin_amdgcn_mfma_f32_16x16x32_bf16(al, bh, acc3, 0, 0, 0);
            acc3 = __builtin_amdgcn_mfma_f32_16x16x32_bf16(ah, bl, acc3, 0, 0, 0);
        }
    }

    int chunk = i * 2 + xh;
    int n = nb * 64 + w * 16 + r;
    float* dst = partial + (size_t)chunk * (B_N * 1024) + n;
#pragma unroll
    for (int reg = 0; reg < 4; ++reg) {
        dst[(0 * 16 + hg * 4 + reg) * 1024] = acc0[reg];
        dst[(1 * 16 + hg * 4 + reg) * 1024] = acc1[reg];
        dst[(2 * 16 + hg * 4 + reg) * 1024] = acc2[reg];
        dst[(3 * 16 + hg * 4 + reg) * 1024] = acc3[reg];
    }
}

// ---------------------------------------------------------------------------
// reduce 64 partials into split-bf16 A for x2: aXh/aXl[b][ck] (ck = n flat)
// ---------------------------------------------------------------------------
__global__ __launch_bounds__(256) void k_reduce(const float4* __restrict__ p,
                                                short4* __restrict__ aXh,
                                                short4* __restrict__ aXl,
                                                int nchunk) {
    int f = blockIdx.x * 256 + threadIdx.x;   // 16384 float4s
    float4 s = make_float4(0.f, 0.f, 0.f, 0.f);
    for (int c = 0; c < nchunk; ++c) {
        float4 v = p[(size_t)c * 16384 + f];
        s.x += v.x; s.y += v.y; s.z += v.z; s.w += v.w;
    }
    short4 h, l;
    bfsplit(s.x, &h.x, &l.x);
    bfsplit(s.y, &h.y, &l.y);
    bfsplit(s.z, &h.z, &l.z);
    bfsplit(s.w, &h.w, &l.w);
    aXh[f] = h;
    aXl[f] = l;
}

// ---------------------------------------------------------------------------
// transpose out1tmp[x][bo] -> out1T[bo][x]
// ---------------------------------------------------------------------------
__global__ __launch_bounds__(256) void k_transpose_o1(const float2* __restrict__ out1tmp,
                                                      float2* __restrict__ out1T) {
    __shared__ float2 T[64 * 33];
    int blk = blockIdx.x;
    int bot = blk >> 5, xt = blk & 31;
    int tid = threadIdx.x;
#pragma unroll
    for (int r = 0; r < 8; ++r) {
        int e = tid + (r << 8);
        int j = e & 63, xr = e >> 6;
        T[j * 33 + xr] = out1tmp[((size_t)(xt * 32 + xr)) * 2048 + bot * 64 + j];
    }
    __syncthreads();
#pragma unroll
    for (int r = 0; r < 8; ++r) {
        int e = tid + (r << 8);
        int xx = e & 31, j = e >> 5;
        out1T[((size_t)(bot * 64 + j)) * T_N + xt * 32 + xx] = T[j * 33 + xx];
    }
}

__global__ __launch_bounds__(256) void k_ifft(const float2* __restrict__ out1T,
                                              float* __restrict__ outp) {
    __shared__ float2 A[1024];
    __shared__ float2 Bb[1024];
    __shared__ float2 TW[512];
    int row = blockIdx.x;
    int tid = threadIdx.x;
    build_tw<1>(TW, tid);
    const float2* src = out1T + (size_t)row * T_N;
#pragma unroll
    for (int r = 0; r < 4; ++r) {
        int j = tid + (r << 8);
        A[j] = src[j];
    }
    fft1024<1>(A, Bb, TW, tid);
    float* dst = outp + (size_t)row * T_N;
    const float inv_n = 1.0f / (float)T_N;
#pragma unroll
    for (int r = 0; r < 4; ++r) {
        int j = tid + (r << 8);
        dst[j] = A[j].x * inv_n;
    }
}

// ---------------------------------------------------------------------------
// x2 MFMA: x2[b,z] += (1/N)*sum_ck A[b,ck]*B[ck,z] per o.
// A[b][cm*2+{R,I}] = o2 (split-bf16 from k_reduce); B[cm*2+0][z]=ERe,
// B[cm*2+1][z]=-EIm, E=exp(pole[c,o,m]*t_z). Grid dim3(zb:16, o:32), 4 waves.
// Same slot-symmetric frag layout as k_out2m. Epilogue RMW-adds into outp
// (x1 already written by k_ifft).
// ---------------------------------------------------------------------------
__global__ __launch_bounds__(256) void k_x2m(const short* __restrict__ aXh,
                                             const short* __restrict__ aXl,
                                             const float* __restrict__ pr,
                                             const float* __restrict__ pim,
                                             float* __restrict__ outp) {
    __shared__ short sAh[64 * ABROW], sAl[64 * ABROW];
    __shared__ short sBh[64 * ABROW], sBl[64 * ABROW];
    __shared__ float s_pr[512], s_pim[512];

    const int zb = blockIdx.x, o = blockIdx.y;
    const int tid = threadIdx.x;
    const int w = tid >> 6, l = tid & 63;
    const int r = l & 15, hg = l >> 4;

#pragma unroll
    for (int rr_ = 0; rr_ < 2; ++rr_) {
        int cm = tid + (rr_ << 8);           // 0..511
        int c = cm >> 4, m = cm & 15;
        int pidx = (c * COUT + o) * MODES + m;
        s_pr[cm] = pr[pidx];
        s_pim[cm] = pim[pidx];
    }
    __syncthreads();

    f32x4 acc0 = {0.f, 0.f, 0.f, 0.f};
    f32x4 acc1 = {0.f, 0.f, 0.f, 0.f};
    f32x4 acc2 = {0.f, 0.f, 0.f, 0.f};
    f32x4 acc3 = {0.f, 0.f, 0.f, 0.f};

    const int sb = tid >> 2;                 // staging row (b)
    const int sc = (tid & 3) * 8;            // staging col (shorts)
    const float z0f = (float)(zb * 64);

    for (int ks = 0; ks < 32; ++ks) {
        __syncthreads();
        // stage A slice [64 b][32 ck]
        *(float4*)&sAh[sb * ABROW + sc] = *(const float4*)&aXh[sb * 1024 + ks * 32 + sc];
        *(float4*)&sAl[sb * ABROW + sc] = *(const float4*)&aXl[sb * 1024 + ks * 32 + sc];
        // build B tile: 16 cm x 64 z complex entries
#pragma unroll
        for (int qq = 0; qq < 4; ++qq) {
            int slot = (qq << 8) + tid;      // 0..1023
            int z = slot & 63, cml = slot >> 6;
            int cm = ks * 16 + cml;
            float gr = s_pr[cm], gi = s_pim[cm];
            float tz = (z0f + (float)z) * DT;
            float er = __expf(gr * tz);
            float sn, cn;
            __sincosf(gi * tz, &sn, &cn);
            int rowb = z * ABROW + cml * 2;
            bfsplit(er * cn,  &sBh[rowb],     &sBl[rowb]);
            bfsplit(-er * sn, &sBh[rowb + 1], &sBl[rowb + 1]);
        }
        __syncthreads();

        bf16x8 bh = *(bf16x8*)&sBh[(w * 16 + r) * ABROW + hg * 8];
        bf16x8 bl = *(bf16x8*)&sBl[(w * 16 + r) * ABROW + hg * 8];
        {
            bf16x8 ah = *(bf16x8*)&sAh[(0 * 16 + r) * ABROW + hg * 8];
            bf16x8 al = *(bf16x8*)&sAl[(0 * 16 + r) * ABROW + hg * 8];
            acc0 = __builtin_amdgcn_mfma_f32_16x16x32_bf16(ah, bh, acc0, 0, 0, 0);
            acc0 = __builtin_amdgcn_mfma_f32_16x16x32_bf16(al, bh, acc0, 0, 0, 0);
            acc0 = __builtin_amdgcn_mfma_f32_16x16x32_bf16(ah, bl, acc0, 0, 0, 0);
        }
        {
            bf16x8 ah = *(bf16x8*)&sAh[(1 * 16 + r) * ABROW + hg * 8];
            bf16x8 al = *(bf16x8*)&sAl[(1 * 16 + r) * ABROW + hg * 8];
            acc1 = __builtin_amdgcn_mfma_f32_16x16x32_bf16(ah, bh, acc1, 0, 0, 0);
            acc1 = __builtin_amdgcn_mfma_f32_16x16x32_bf16(al, bh, acc1, 0, 0, 0);
            acc1 = __builtin_amdgcn_mfma_f32_16x16x32_bf16(ah, bl, acc1, 0, 0, 0);
        }
        {
            bf16x8 ah = *(bf16x8*)&sAh[(2 * 16 + r) * ABROW + hg * 8];
            bf16x8 al = *(bf16x8*)&sAl[(2 * 16 + r) * ABROW + hg * 8];
            acc2 = __builtin_amdgcn_mfma_f32_16x16x32_bf16(ah, bh, acc2, 0, 0, 0);
            acc2 = __builtin_amdgcn_mfma_f32_16x16x32_bf16(al, bh, acc2, 0, 0, 0);
            acc2 = __builtin_amdgcn_mfma_f32_16x16x32_bf16(ah, bl, acc2, 0, 0, 0);
        }
        {
            bf16x8 ah = *(bf16x8*)&sAh[(3 * 16 + r) * ABROW + hg * 8];
            bf16x8 al = *(bf16x8*)&sAl[(3 * 16 + r) * ABROW + hg * 8];
            acc3 = __builtin_amdgcn_mfma_f32_16x16x32_bf16(ah, bh, acc3, 0, 0, 0);
            acc3 = __builtin_amdgcn_mfma_f32_16x16x32_bf16(al, bh, acc3, 0, 0, 0);
            acc3 = __builtin_amdgcn_mfma_f32_16x16x32_bf16(ah, bl, acc3, 0, 0, 0);
        }
    }

    // epilogue: RMW add; C/D layout col=lane&15 (z), row=(lane>>4)*4+reg (b)
    const float inv_n = 1.0f / (float)T_N;
    size_t base = (size_t)o * T_N + zb * 64 + w * 16 + r;
#pragma unroll
    for (int reg = 0; reg < 4; ++reg) {
        size_t i0 = base + (size_t)(0 * 16 + hg * 4 + reg) * (COUT * T_N);
        size_t i1 = base + (size_t)(1 * 16 + hg * 4 + reg) * (COUT * T_N);
        size_t i2 = base + (size_t)(2 * 16 + hg * 4 + reg) * (COUT * T_N);
        size_t i3 = base + (size_t)(3 * 16 + hg * 4 + reg) * (COUT * T_N);
        outp[i0] += acc0[reg] * inv_n;
        outp[i1] += acc1[reg] * inv_n;
        outp[i2] += acc2[reg] * inv_n;
        outp[i3] += acc3[reg] * inv_n;
    }
}

// ---------------------------------------------------------------------------
extern "C" void kernel_launch(void* const* d_in, const int* in_sizes, int n_in,
                              void* d_out, int out_size, void* d_ws, size_t ws_size,
                              hipStream_t stream) {
    const float* x   = (const float*)d_in[0];
    const float* pr  = (const float*)d_in[2];
    const float* pim = (const float*)d_in[3];
    const float* rr  = (const float*)d_in[4];
    const float* ri  = (const float*)d_in[5];
    float* outp = (float*)d_out;

    char* ws = (char*)d_ws;
    const size_t MB = 1024 * 1024;
    const size_t KB = 1024;
    float2* alpha   = (float2*)ws;                     // [0,16M)
    float2* alphaT  = (float2*)(ws + 16 * MB);         // [16M,32M)
    short*  aXh     = (short*)(ws + 32 * MB);          // [32M,+128K)
    short*  aXl     = (short*)(ws + 32 * MB + 128 * KB); // [+128K,+256K)
    short*  aHi     = (short*)(ws + 33 * MB);          // [33M,37M)
    short*  aLo     = (short*)(ws + 37 * MB);          // [37M,41M)
    float*  o2part;
    if (ws_size >= (size_t)(57 * MB)) {
        o2part = (float*)(ws + 41 * MB);               // [41M,57M): 64 x 256KB
    } else {
        o2part = (float*)ws;                           // region A (alpha dead)
    }
    float2* out1tmp = (float2*)ws;                     // region A (after reduce)
    float2* out1T   = (float2*)(ws + 16 * MB);         // region B (alphaT dead)

    k_fft_fwd     <<<B_N * CIN, 256, 0, stream>>>(x, alpha);
    k_transpose_a <<<CIN * 32, 256, 0, stream>>>(alpha, alphaT);
    k_conv        <<<B_N * CIN, 256, 0, stream>>>(alpha, aHi, aLo);
    k_out2m       <<<dim3(16, 2, 32), 256, 0, stream>>>(aHi, aLo,
                                                        pr, pim, rr, ri, o2part);
    k_reduce      <<<64, 256, 0, stream>>>((const float4*)o2part,
                                           (short4*)aXh, (short4*)aXl, 64);
    k_out1        <<<T_N, 256, 0, stream>>>((const float4*)alphaT,
                                            pr, pim, rr, ri, out1tmp);
    k_transpose_o1<<<32 * 32, 256, 0, stream>>>(out1tmp, out1T);
    k_ifft        <<<B_N * COUT, 256, 0, stream>>>(out1T, outp);
    k_x2m         <<<dim3(16, 32), 256, 0, stream>>>(aXh, aXl, pr, pim, outp);
}